// Round 11
// baseline (231.917 us; speedup 1.0000x reference)
//
#include <hip/hip_runtime.h>
#include <stdint.h>

#define DI __device__ __forceinline__

typedef __attribute__((ext_vector_type(8))) __bf16 bf16x8;
typedef __attribute__((ext_vector_type(8))) unsigned short u16x8;
typedef __attribute__((ext_vector_type(4))) float f32x4;
typedef __attribute__((ext_vector_type(4))) uint32_t u32x4;
typedef unsigned short u16;

constexpr int Bb = 4, Cc = 256, Ss = 4096, HD = 64;
constexpr int ELEMS = Bb * Cc * Ss;  // 4194304

DI float bf2f(u16 h) { union { unsigned u; float f; } x; x.u = ((unsigned)h) << 16; return x.f; }
DI u16 f2bf(float f) {
  union { float f; unsigned u; } x; x.f = f;
  return (u16)((x.u + 0x7FFFu + ((x.u >> 16) & 1u)) >> 16);
}
DI uint32_t pack2bf_trunc(float a, float b) {  // low16=bf(a), high16=bf(b), truncating
  union { float f; uint32_t u; } xa, xb;
  xa.f = a; xb.f = b;
  return __builtin_amdgcn_perm(xb.u, xa.u, 0x07060302u);
}
DI bf16x8 ldfrag(const u16* p) { return __builtin_bit_cast(bf16x8, *(const u16x8*)p); }

// ---------------- kernel 0: x (B,C,S) fp32 -> xt (B,S,C) bf16; + weight conversion fused ----------------
__global__ __launch_bounds__(256) void k_transpose(const float* __restrict__ x, u16* __restrict__ xt,
                                                   const float* __restrict__ wq, const float* __restrict__ wo,
                                                   u16* __restrict__ wqb, u16* __restrict__ wob) {
  __shared__ u16 T[64][72];
  const int st = blockIdx.x, ct = blockIdx.y, b = blockIdx.z;
  const int tid = threadIdx.x;
  {
    int flat = blockIdx.x + 64 * blockIdx.y + 256 * blockIdx.z;
    int widx = flat * 256 + tid;
    if (widx < 196608) wqb[widx] = f2bf(wq[widx]);
    else wob[widx - 196608] = f2bf(wo[widx - 196608]);
  }
#pragma unroll
  for (int e = 0; e < 2; e++) {
    int ss = tid + e * 256;
    int r = ss >> 3, seg = ss & 7;
    size_t base = ((size_t)(b * Cc + ct * 64 + r) << 12) + st * 64 + seg * 8;
    u16x8 t;
#pragma unroll
    for (int j = 0; j < 8; j++) t[j] = f2bf(x[base + j]);
    *(u16x8*)&T[r][(seg ^ ((r >> 3) & 7)) * 8] = t;
  }
  __syncthreads();
#pragma unroll
  for (int e = 0; e < 2; e++) {
    int ss = tid + e * 256;
    int sr = ss >> 3, cseg = ss & 7;
    u16x8 o;
#pragma unroll
    for (int j = 0; j < 8; j++) {
      int row = cseg * 8 + j;
      o[j] = T[row][(((sr >> 3) ^ cseg) * 8) + (sr & 7)];
    }
    *(u16x8*)(xt + ((size_t)(b * Ss + st * 64 + sr) << 8) + ct * 64 + cseg * 8) = o;
  }
}

// ---- shared GEMM staging: rows [r0,r0+128) x cols [k0,k0+32), pitch-40 LDS ----
DI void stage_tile(const u16* __restrict__ src, int pitch, int r0, int k0, u16 (*dst)[40], int tid) {
#pragma unroll
  for (int e = 0; e < 2; e++) {
    int c = tid + e * 256;
    int row = c >> 2, seg = c & 3;
    u16x8 t = *(const u16x8*)(src + (size_t)(r0 + row) * pitch + k0 + seg * 8);
    *(u16x8*)&dst[row][seg * 8] = t;
  }
}

// ---------------- kernel 1: qkv GEMM.  q:[bh][s][64]*(0.125*log2e)  k,v:[bh][s][64] ----------------
__global__ __launch_bounds__(256) void k_qkv(const u16* __restrict__ xt, const u16* __restrict__ w,
                                             const float* __restrict__ bias,
                                             u16* __restrict__ q, u16* __restrict__ kk_, u16* __restrict__ vv_) {
  __shared__ u16 As[128][40], Bs[128][40];
  const int tid = threadIdx.x;
  const int wv = tid >> 6, lane = tid & 63;
  const int wm = wv >> 1, wn = wv & 1;
  const int lr = lane & 15, quad = lane >> 4;
  const int r0 = blockIdx.x * 128;
  const int j0 = blockIdx.y * 128;
  f32x4 acc[4][4] = {};
  for (int k0 = 0; k0 < 256; k0 += 32) {
    __syncthreads();
    stage_tile(xt, 256, r0, k0, As, tid);
    stage_tile(w, 256, j0, k0, Bs, tid);
    __syncthreads();
    bf16x8 a[4], b[4];
#pragma unroll
    for (int mt = 0; mt < 4; mt++) a[mt] = ldfrag(&As[wm * 64 + mt * 16 + lr][quad * 8]);
#pragma unroll
    for (int nt = 0; nt < 4; nt++) b[nt] = ldfrag(&Bs[wn * 64 + nt * 16 + lr][quad * 8]);
#pragma unroll
    for (int mt = 0; mt < 4; mt++)
#pragma unroll
      for (int nt = 0; nt < 4; nt++)
        acc[mt][nt] = __builtin_amdgcn_mfma_f32_16x16x32_bf16(a[mt], b[nt], acc[mt][nt], 0, 0, 0);
  }
#pragma unroll
  for (int nt = 0; nt < 4; nt++) {
    int j = j0 + wn * 64 + nt * 16 + lr;
    float bj = bias[j];
    int part = j >> 8, cc = j & 255, head = cc >> 6, d = cc & 63;
    u16* outp = (part == 0) ? q : (part == 1) ? kk_ : vv_;
    float sc = (part == 0) ? 0.18033688f : 1.0f;  // 0.125*log2(e), exp2-domain scores
#pragma unroll
    for (int mt = 0; mt < 4; mt++)
#pragma unroll
      for (int rg = 0; rg < 4; rg++) {
        int row = r0 + wm * 64 + mt * 16 + quad * 4 + rg;
        int b_ = row >> 12, s = row & 4095;
        outp[((size_t)((b_ * 4 + head) * Ss + s) << 6) + d] = f2bf((acc[mt][nt][rg] + bj) * sc);
      }
  }
}

// ---------------- v [bh][s][64] -> vt [bh][d][chunk*64 + slot] (key-permuted transpose) ----------------
__global__ __launch_bounds__(256) void k_vt(const u16* __restrict__ v, u16* __restrict__ vt) {
  __shared__ u16 T[64][72];
  const int chunk = blockIdx.x, bh = blockIdx.y;
  const int tid = threadIdx.x;
#pragma unroll
  for (int e = 0; e < 2; e++) {
    int row = (tid >> 3) + e * 32, seg = tid & 7;
    *(u16x8*)&T[row][(seg ^ ((row >> 3) & 7)) * 8] =
        *(const u16x8*)(v + ((size_t)(bh * Ss + chunk * 64 + row) << 6) + seg * 8);
  }
  __syncthreads();
#pragma unroll
  for (int e = 0; e < 2; e++) {
    int d = (tid >> 3) + e * 32, seg = tid & 7;
    u16x8 o;
#pragma unroll
    for (int j = 0; j < 8; j++) {
      int slot = seg * 8 + j;
      int t = (((slot >> 5) & 1) << 1) | ((slot >> 2) & 1);
      int w6 = t * 16 + (((slot >> 3) & 3) << 2) + (slot & 3);
      o[j] = T[w6][(((d >> 3) ^ ((w6 >> 3) & 7)) * 8) + (d & 7)];
    }
    *(u16x8*)(vt + ((size_t)(bh * 64 + d) << 12) + chunk * 64 + seg * 8) = o;
  }
}

// ---------------- kernel 2: flash attention, S^T form, exp2 no-max softmax, NO LDS ----------------
// Frags read directly from global (L2-resident K/VT; frag loads are 16 rows x 64B lines).
// No barriers — waves fully independent. grid.x = bh for XCD/L2 locality.
__global__ __launch_bounds__(256) void k_attn(const u16* __restrict__ Q, const u16* __restrict__ K,
                                              const u16* __restrict__ VT, u16* __restrict__ AO,
                                              u16* __restrict__ AOP, float* __restrict__ lpart,
                                              int nsplit) {
  const int tid = threadIdx.x;
  const int wv = tid >> 6, lane = tid & 63;
  const int lr = lane & 15, quad = lane >> 4;
  const int bh = blockIdx.x;
  const int b_ = bh >> 2, head = bh & 3;
  const int qbase = blockIdx.y * 256 + wv * 64;
  const int sp = blockIdx.z;
  const int nchunk = 64 / nsplit, kcg0 = sp * nchunk;
  const u16* Qh = Q + (size_t)bh * Ss * HD;
  const u16* Kh = K + (size_t)bh * Ss * HD;
  const u16* Vh = VT + (size_t)bh * HD * Ss;  // [d][perm(s)]

  bf16x8 qb[4][2];
#pragma unroll
  for (int nt = 0; nt < 4; nt++)
#pragma unroll
    for (int ks = 0; ks < 2; ks++)
      qb[nt][ks] = ldfrag(Qh + (size_t)(qbase + nt * 16 + lr) * HD + ks * 32 + quad * 8);

  u16x8 ov;
#pragma unroll
  for (int j = 0; j < 8; j++) ov[j] = 0x3F80;
  const bf16x8 ones = __builtin_bit_cast(bf16x8, ov);

  f32x4 O[4][4] = {};
  f32x4 lacc[4] = {};

  for (int kc = 0; kc < nchunk; kc++) {
    const int kabs = kcg0 + kc;
    // K frags direct from global: row = key (128B stride), 64B used per row
    f32x4 St[4][4] = {};
#pragma unroll
    for (int ks = 0; ks < 2; ks++) {
      bf16x8 ka[4];
#pragma unroll
      for (int kt = 0; kt < 4; kt++)
        ka[kt] = ldfrag(Kh + ((size_t)(kabs * 64 + kt * 16 + lr) << 6) + ks * 32 + quad * 8);
#pragma unroll
      for (int kt = 0; kt < 4; kt++)
#pragma unroll
        for (int nt = 0; nt < 4; nt++)
          St[kt][nt] = __builtin_amdgcn_mfma_f32_16x16x32_bf16(ka[kt], qb[nt][ks], St[kt][nt], 0, 0, 0);
    }

    uint32_t pk[4][4][2];
#pragma unroll
    for (int kt = 0; kt < 4; kt++)
#pragma unroll
      for (int nt = 0; nt < 4; nt++) {
        float p0 = __builtin_amdgcn_exp2f(St[kt][nt][0]);
        float p1 = __builtin_amdgcn_exp2f(St[kt][nt][1]);
        float p2 = __builtin_amdgcn_exp2f(St[kt][nt][2]);
        float p3 = __builtin_amdgcn_exp2f(St[kt][nt][3]);
        pk[kt][nt][0] = pack2bf_trunc(p0, p1);
        pk[kt][nt][1] = pack2bf_trunc(p2, p3);
      }

#pragma unroll
    for (int ks = 0; ks < 2; ks++) {
      bf16x8 pa[4];
#pragma unroll
      for (int mt = 0; mt < 4; mt++) {
        u32x4 t = {pk[2 * ks][mt][0], pk[2 * ks][mt][1], pk[2 * ks + 1][mt][0], pk[2 * ks + 1][mt][1]};
        pa[mt] = __builtin_bit_cast(bf16x8, t);
      }
#pragma unroll
      for (int dt = 0; dt < 4; dt++) {
        // V frags direct from global VT: row = d (8KB stride), 64B used per row
        bf16x8 vb = ldfrag(Vh + ((size_t)(dt * 16 + lr) << 12) + kabs * 64 + ks * 32 + quad * 8);
#pragma unroll
        for (int mt = 0; mt < 4; mt++)
          O[mt][dt] = __builtin_amdgcn_mfma_f32_16x16x32_bf16(pa[mt], vb, O[mt][dt], 0, 0, 0);
      }
#pragma unroll
      for (int mt = 0; mt < 4; mt++)
        lacc[mt] = __builtin_amdgcn_mfma_f32_16x16x32_bf16(pa[mt], ones, lacc[mt], 0, 0, 0);
    }
  }

  // epilogue: normalize by this split's l, write bf16 (AO if nsplit==1, else partial slot sp)
  u16* dst = (nsplit == 1) ? AO : (AOP + (size_t)sp * ELEMS);
  if (nsplit > 1 && lr == 0) {
    float* lp = lpart + (size_t)sp * (16 * Ss) + bh * Ss;
#pragma unroll
    for (int mt = 0; mt < 4; mt++)
#pragma unroll
      for (int rg = 0; rg < 4; rg++) lp[qbase + mt * 16 + quad * 4 + rg] = lacc[mt][rg];
  }
#pragma unroll
  for (int mt = 0; mt < 4; mt++)
#pragma unroll
    for (int rg = 0; rg < 4; rg++) {
      float inv = 1.0f / lacc[mt][rg];
      int s = qbase + mt * 16 + quad * 4 + rg;
#pragma unroll
      for (int dt = 0; dt < 4; dt++)
        dst[((size_t)(b_ * Ss + s) << 8) + head * 64 + dt * 16 + lr] = f2bf(O[mt][dt][rg] * inv);
    }
}

// ---------------- kernel 3 (fused combine + oproj): y^T = w_o * combine(aop)^T + b_o ----------------
__global__ __launch_bounds__(512) void k_oproj(const u16* __restrict__ wo, const u16* __restrict__ ao,
                                               const u16* __restrict__ AOP, const float* __restrict__ lpart,
                                               const float* __restrict__ bo, float* __restrict__ y, int nsplit) {
  __shared__ u16 As[256][40], Bs[128][40];
  const int tid = threadIdx.x;
  const int wv = tid >> 6, lane = tid & 63;
  const int wm = wv >> 1, wn = wv & 1;
  const int lr = lane & 15, quad = lane >> 4;
  const int n0 = blockIdx.x * 128;
  f32x4 acc[4][4] = {};
  for (int k0 = 0; k0 < 256; k0 += 32) {
    __syncthreads();
#pragma unroll
    for (int e = 0; e < 2; e++) {
      int c = tid + e * 512;
      int row = c >> 2, seg = c & 3;
      *(u16x8*)&As[row][seg * 8] = *(const u16x8*)(wo + row * 256 + k0 + seg * 8);
    }
    {
      int row = tid >> 2, seg = tid & 3;
      int bs = n0 + row, cc = k0 + seg * 8;
      u16x8 t;
      if (nsplit == 1) {
        t = *(const u16x8*)(ao + ((size_t)bs << 8) + cc);
      } else {
        int b = bs >> 12, s = bs & 4095, head = cc >> 6;
        int li = (b * 4 + head) * Ss + s;
        u16x8 a0 = *(const u16x8*)(AOP + ((size_t)bs << 8) + cc);
        u16x8 a1 = *(const u16x8*)(AOP + (size_t)ELEMS + ((size_t)bs << 8) + cc);
        float l0 = lpart[li], l1 = lpart[16 * Ss + li];
        float inv = 1.0f / (l0 + l1);
        float w0 = l0 * inv, w1 = l1 * inv;
#pragma unroll
        for (int i = 0; i < 8; i++) t[i] = f2bf(w0 * bf2f(a0[i]) + w1 * bf2f(a1[i]));
      }
      *(u16x8*)&Bs[row][seg * 8] = t;
    }
    __syncthreads();
    bf16x8 a[4], b[4];
#pragma unroll
    for (int mt = 0; mt < 4; mt++) a[mt] = ldfrag(&As[wm * 64 + mt * 16 + lr][quad * 8]);
#pragma unroll
    for (int nt = 0; nt < 4; nt++) b[nt] = ldfrag(&Bs[wn * 64 + nt * 16 + lr][quad * 8]);
#pragma unroll
    for (int mt = 0; mt < 4; mt++)
#pragma unroll
      for (int nt = 0; nt < 4; nt++)
        acc[mt][nt] = __builtin_amdgcn_mfma_f32_16x16x32_bf16(a[mt], b[nt], acc[mt][nt], 0, 0, 0);
  }
#pragma unroll
  for (int mt = 0; mt < 4; mt++)
#pragma unroll
    for (int rg = 0; rg < 4; rg++) {
      int c = wm * 64 + mt * 16 + quad * 4 + rg;
      float bc = bo[c];
#pragma unroll
      for (int nt = 0; nt < 4; nt++) {
        int col = n0 + wn * 64 + nt * 16 + lr;
        int b_ = col >> 12, s = col & 4095;
        y[((size_t)(b_ * Cc + c) << 12) + s] = acc[mt][nt][rg] + bc;
      }
    }
}

extern "C" void kernel_launch(void* const* d_in, const int* in_sizes, int n_in,
                              void* d_out, int out_size, void* d_ws, size_t ws_size,
                              hipStream_t stream) {
  const float* x = (const float*)d_in[0];
  const float* w_qkv = (const float*)d_in[1];
  const float* b_qkv = (const float*)d_in[2];
  const float* w_o = (const float*)d_in[3];
  const float* b_o = (const float*)d_in[4];
  float* y = (float*)d_out;
  u16* ws = (u16*)d_ws;
  u16* xt = ws;                        // [0, E) — reused as ao (nsplit==1 fallback)
  u16* q = ws + (size_t)ELEMS;
  u16* k = ws + (size_t)2 * ELEMS;
  u16* vt = ws + (size_t)3 * ELEMS;
  u16* ao = xt;
  u16* wqb = ws + (size_t)4 * ELEMS;   // 196608
  u16* wob = wqb + 196608;             // 65536
  const size_t Wu16 = (size_t)4 * ELEMS + 262144;
  u16* aop = ws + Wu16;                // 2*ELEMS u16 normalized partials
  u16* v = aop;                        // plain V aliases aop (dead before k_attn writes)
  float* lpart = (float*)(aop + (size_t)2 * ELEMS);
  const size_t need = (Wu16 + (size_t)2 * ELEMS) * 2 + (size_t)2 * 16 * Ss * 4;
  const int nsplit = (ws_size >= need) ? 2 : 1;

  k_transpose<<<dim3(64, 4, 4), 256, 0, stream>>>(x, xt, w_qkv, w_o, wqb, wob);
  k_qkv<<<dim3(128, 6), 256, 0, stream>>>(xt, wqb, b_qkv, q, k, v);
  k_vt<<<dim3(64, 16), 256, 0, stream>>>(v, vt);
  k_attn<<<dim3(16, 16, nsplit), 256, 0, stream>>>(q, k, vt, ao, aop, lpart, nsplit);
  k_oproj<<<128, 512, 0, stream>>>(wob, ao, aop, lpart, b_o, y, nsplit);
}